// Round 7
// baseline (486.663 us; speedup 1.0000x reference)
//
#include <hip/hip_runtime.h>
#include <hip/hip_bf16.h>

#define N_ 8
#define C_ 256
#define HW_ 4096
#define CNT_ (C_*HW_)

typedef __attribute__((ext_vector_type(8))) short bf16x8;
typedef __attribute__((ext_vector_type(4))) float f32x4;
typedef __attribute__((ext_vector_type(16))) float f32x16;

__device__ inline float exp2fast(float x){ return __builtin_amdgcn_exp2f(x); }

__device__ inline unsigned short f2bf(float f){
  union{float f; unsigned u;} v; v.f=f;
  unsigned r = v.u + 0x7fff + ((v.u>>16)&1);
  return (unsigned short)(r>>16);
}
__device__ inline float bf2f(unsigned short h){
  union{unsigned u; float f;} v; v.u = ((unsigned)h)<<16; return v.f;
}

__device__ inline f32x4 mfma16(bf16x8 a, bf16x8 b, f32x4 c){
  return __builtin_amdgcn_mfma_f32_16x16x32_bf16(a,b,c,0,0,0);
}
__device__ inline f32x16 mfma32(bf16x8 a, bf16x8 b, f32x16 c){
  return __builtin_amdgcn_mfma_f32_32x32x16_bf16(a,b,c,0,0,0);
}

#define GLL16(gp, lp) __builtin_amdgcn_global_load_lds( \
    (__attribute__((address_space(1))) void*)(gp), \
    (__attribute__((address_space(3))) void*)(lp), 16, 0, 0)

// ---------------- weight convert (fp32 -> bf16) ----------------
__global__ void k_cvt(const float* __restrict__ src, unsigned short* __restrict__ dst){
  int i = blockIdx.x*256 + threadIdx.x;
  dst[i] = f2bf(src[i]);
}

// ---------------- layernorm stats, stage 1 ----------------
__global__ void k_stats1(const float* __restrict__ x, float2* __restrict__ part){
  int n = blockIdx.x >> 8;
  int chunk = blockIdx.x & 255;
  const float4* p = (const float4*)(x + (size_t)n*CNT_ + (size_t)chunk*4096);
  int t = threadIdx.x;
  float s=0.f, s2=0.f;
  #pragma unroll
  for(int i=0;i<4;i++){
    float4 v = p[t + 256*i];
    s  += v.x+v.y+v.z+v.w;
    s2 += v.x*v.x+v.y*v.y+v.z*v.z+v.w*v.w;
  }
  #pragma unroll
  for(int o=32;o;o>>=1){ s += __shfl_down(s,o); s2 += __shfl_down(s2,o); }
  __shared__ float sh[4], sh2[4];
  int lane = t&63, wid = t>>6;
  if(lane==0){ sh[wid]=s; sh2[wid]=s2; }
  __syncthreads();
  if(t==0){
    float2 r; r.x = sh[0]+sh[1]+sh[2]+sh[3]; r.y = sh2[0]+sh2[1]+sh2[2]+sh2[3];
    part[blockIdx.x] = r;
  }
}

// ---------------- layernorm stats, stage 2 ----------------
__global__ void k_stats2(const float2* __restrict__ part, float2* __restrict__ stats){
  int n = blockIdx.x, t = threadIdx.x;
  float2 v = part[n*256 + t];
  float s = v.x, s2 = v.y;
  #pragma unroll
  for(int o=32;o;o>>=1){ s += __shfl_down(s,o); s2 += __shfl_down(s2,o); }
  __shared__ float sh[4], sh2[4];
  int lane = t&63, wid = t>>6;
  if(lane==0){ sh[wid]=s; sh2[wid]=s2; }
  __syncthreads();
  if(t==0){
    s = sh[0]+sh[1]+sh[2]+sh[3];
    s2 = sh2[0]+sh2[1]+sh2[2]+sh2[3];
    float mean = s * (1.f/(float)CNT_);
    float var  = s2 * (1.f/(float)CNT_) - mean*mean;
    float2 r; r.x = mean; r.y = rsqrtf(var + 1e-5f);
    stats[n] = r;
  }
}

// ---------------- normalize + transpose to NHWC bf16 ----------------
__global__ void k_norm(const float* __restrict__ x, const float* __restrict__ lnw,
                       const float* __restrict__ lnb, const float2* __restrict__ stats,
                       unsigned short* __restrict__ nx){
  __shared__ float tile[64][65];
  int n = blockIdx.z, c0 = blockIdx.y*64, p0 = blockIdx.x*64;
  float2 st = stats[n];
  float mu = st.x, rs = st.y;
  int t = threadIdx.x, col = t&63, rw = t>>6;
  #pragma unroll
  for(int pass=0; pass<16; pass++){
    int row = pass*4 + rw;
    size_t gi = (size_t)(c0+row)*HW_ + (p0+col);
    float v = x[(size_t)n*CNT_ + gi];
    tile[row][col] = (v - mu)*rs*lnw[gi] + lnb[gi];
  }
  __syncthreads();
  #pragma unroll
  for(int pass=0; pass<16; pass++){
    int prow = pass*4 + rw;
    nx[((size_t)n*HW_ + p0+prow)*C_ + c0 + col] = f2bf(tile[col][prow]);
  }
}

// ---------------- strip GEMM: D[row][col] = (sum_k A[row][k]*B[col][k] + bias)*scale ----
__global__ void k_gemm(const unsigned short* __restrict__ Abase, long strideA,
                       const unsigned short* __restrict__ Bbase, long strideB,
                       const float* __restrict__ bias, int bias_row, float scale,
                       unsigned short* __restrict__ Out, long strideO, int ldo){
  int n = blockIdx.z;
  const unsigned short* A = Abase + (size_t)n*strideA;
  const unsigned short* B = Bbase + (size_t)n*strideB;
  unsigned short* O = Out + (size_t)n*strideO;
  int t = threadIdx.x, w = t>>6, l = t&63, ri = l&15, k8 = (l>>4)*8;
  int row0 = blockIdx.x*64 + w*16;
  int col0 = blockIdx.y*64;
  f32x4 zero = {0.f,0.f,0.f,0.f};
  f32x4 acc[4] = {zero, zero, zero, zero};
  #pragma unroll
  for(int k=0;k<256;k+=32){
    bf16x8 a = *(const bf16x8*)(A + (size_t)(row0+ri)*256 + k + k8);
    #pragma unroll
    for(int j=0;j<4;j++){
      bf16x8 b = *(const bf16x8*)(B + (size_t)(col0+j*16+ri)*256 + k + k8);
      acc[j] = mfma16(a,b,acc[j]);
    }
  }
  #pragma unroll
  for(int j=0;j<4;j++){
    #pragma unroll
    for(int r=0;r<4;r++){
      int row = row0 + (l>>4)*4 + r;
      int col = col0 + j*16 + ri;
      float d = (acc[j][r] + (bias_row ? bias[row] : bias[col]))*scale;
      O[(size_t)row*ldo + col] = f2bf(d);
    }
  }
}

// ---------------- flash attention: BJ=64 per barrier pair ----------------
// 512 blocks x 256 threads. Block = (batch nb, q-tile of 128, j-half of 2048).
// Wave w owns q-strip of 32. Per iter stages K[64][512B] (XOR-swizzled, 32 KB)
// + V[256][144B] (36 KB) once, then two 32-j sub-steps (dual QK chains).
// 68 KB LDS -> 2 blocks/CU. Cross-half exchange via v_permlane32_swap_b32.
__global__ __launch_bounds__(256, 2) void k_attn5(const unsigned short* __restrict__ qt,
                                                  const unsigned short* __restrict__ kt,
                                                  const unsigned short* __restrict__ vv,
                                                  unsigned short* __restrict__ pO0,
                                                  unsigned short* __restrict__ pO1,
                                                  float2* __restrict__ pml){
  __shared__ __align__(16) char lds[69632];   // 32768 K + 36864 V
  int t = threadIdx.x, w = t>>6, l = t&63, hi = l>>5, lo5 = l&31;
  int nb = blockIdx.x & 7, rem = blockIdx.x >> 3;
  int qb = rem >> 1, jh = rem & 1;
  int q0 = qb*128 + w*32;
  const char* kb = (const char*)(kt + (size_t)nb*HW_*C_);
  const char* vb = (const char*)(vv + (size_t)nb*C_*HW_);
  const char* qp = (const char*)(qt + (size_t)nb*HW_*C_);
  int jbase = jh*2048;
  const int VOFF = 32768;

  bf16x8 qf[16];
  #pragma unroll
  for(int ds=0; ds<16; ds++)
    qf[ds] = *(const bf16x8*)(qp + ((size_t)(q0+lo5)<<9) + ds*32 + hi*16);

  f32x16 o[8];
  #pragma unroll
  for(int dt=0;dt<8;dt++){
    #pragma unroll
    for(int r=0;r<16;r++) o[dt][r]=0.f;
  }
  float m = -1e30f, lsum = 0.f;

  for(int it=0; it<32; ++it){
    int j0 = jbase + it*64;
    // stage K [64 rows][512B], slot-swizzled: row r slot s holds d-slice (s^r)
    #pragma unroll
    for(int k=0;k<8;k++){
      int i = w*8+k;                 // 0..31, 1 KB each (2 rows)
      int row = 2*i + hi;
      GLL16(kb + ((size_t)(j0+row)<<9) + (((lo5^row)&31)<<4), lds + (i<<10));
    }
    // stage V [256 rows][144B: 128 data + 16 pad]
    #pragma unroll
    for(int k=0;k<9;k++){
      int g = w*9+k;                 // 0..35, 1 KB each
      int c = g*64 + l;              // slot id 0..2303
      int d = c/9; int sg = c - d*9; sg = (sg==8)?0:sg;
      GLL16(vb + ((size_t)d<<13) + ((size_t)j0<<1) + (sg<<4), lds + VOFF + (g<<10));
    }
    __syncthreads();   // vmcnt(0)+lgkmcnt(0): tiles ready

    // QK^T, dual independent chains: Sa = j[0,32), Sb = j[32,64); lane holds q=lo5
    f32x16 Sa, Sb;
    #pragma unroll
    for(int r=0;r<16;r++){ Sa[r]=0.f; Sb[r]=0.f; }
    __builtin_amdgcn_s_setprio(1);
    #pragma unroll
    for(int ds=0; ds<16; ds++){
      int slot = (((ds<<1)|hi)^lo5)<<4;
      bf16x8 ka = *(const bf16x8*)(lds + (lo5<<9) + slot);
      bf16x8 kb2 = *(const bf16x8*)(lds + ((32+lo5)<<9) + slot);
      Sa = mfma32(ka, qf[ds], Sa);
      Sb = mfma32(kb2, qf[ds], Sb);
    }
    __builtin_amdgcn_s_setprio(0);

    // joint online softmax (base-2; Q pre-scaled by log2e/16)
    float p0 = fmaxf(Sa[0],Sb[0]);
    #pragma unroll
    for(int r=1;r<16;r++) p0 = fmaxf(p0, fmaxf(Sa[r],Sb[r]));
    float mx = p0;
    { float mA = mx, mB = mx;
      asm("v_permlane32_swap_b32 %0, %1" : "+v"(mA), "+v"(mB));
      mx = fmaxf(mA, mB); }
    if (!__all(mx <= m + 11.5f)){
      float mn = fmaxf(m, mx);
      float al = exp2fast(m - mn);
      lsum *= al;
      #pragma unroll
      for(int dt=0;dt<8;dt++) o[dt] = o[dt] * al;
      m = mn;
    }

    float rs = 0.f;
    // ---- sub-step a: exp + PV for j[0,32) ----
    unsigned pk[8];
    #pragma unroll
    for(int tt=0;tt<8;tt++){
      float pa = exp2fast(Sa[2*tt]-m), pb = exp2fast(Sa[2*tt+1]-m);
      rs += pa + pb;
      unsigned pr;
      asm("v_cvt_pk_bf16_f32 %0, %1, %2" : "=v"(pr) : "v"(pa), "v"(pb));
      pk[tt] = pr;
    }
    __builtin_amdgcn_s_setprio(1);
    {
      unsigned a0 = pk[0], b0 = pk[2], a1 = pk[1], b1 = pk[3];
      asm("v_permlane32_swap_b32 %0, %1" : "+v"(a0), "+v"(b0));
      asm("v_permlane32_swap_b32 %0, %1" : "+v"(a1), "+v"(b1));
      union { unsigned u[4]; bf16x8 v; } F0;
      F0.u[0] = a0; F0.u[1] = a1; F0.u[2] = b0; F0.u[3] = b1;
      #pragma unroll
      for(int dt=0;dt<8;dt++){
        bf16x8 v0 = *(const bf16x8*)(lds + VOFF + (dt*32+lo5)*144 + hi*16);
        o[dt] = mfma32(v0, F0.v, o[dt]);
      }
    }
    {
      unsigned a0 = pk[4], b0 = pk[6], a1 = pk[5], b1 = pk[7];
      asm("v_permlane32_swap_b32 %0, %1" : "+v"(a0), "+v"(b0));
      asm("v_permlane32_swap_b32 %0, %1" : "+v"(a1), "+v"(b1));
      union { unsigned u[4]; bf16x8 v; } F1;
      F1.u[0] = a0; F1.u[1] = a1; F1.u[2] = b0; F1.u[3] = b1;
      #pragma unroll
      for(int dt=0;dt<8;dt++){
        bf16x8 v1 = *(const bf16x8*)(lds + VOFF + (dt*32+lo5)*144 + 32 + hi*16);
        o[dt] = mfma32(v1, F1.v, o[dt]);
      }
    }
    __builtin_amdgcn_s_setprio(0);
    // ---- sub-step b: exp + PV for j[32,64) ----
    #pragma unroll
    for(int tt=0;tt<8;tt++){
      float pa = exp2fast(Sb[2*tt]-m), pb = exp2fast(Sb[2*tt+1]-m);
      rs += pa + pb;
      unsigned pr;
      asm("v_cvt_pk_bf16_f32 %0, %1, %2" : "=v"(pr) : "v"(pa), "v"(pb));
      pk[tt] = pr;
    }
    { float rA = rs, rB = rs;
      asm("v_permlane32_swap_b32 %0, %1" : "+v"(rA), "+v"(rB));
      lsum += rA + rB; }
    __builtin_amdgcn_s_setprio(1);
    {
      unsigned a0 = pk[0], b0 = pk[2], a1 = pk[1], b1 = pk[3];
      asm("v_permlane32_swap_b32 %0, %1" : "+v"(a0), "+v"(b0));
      asm("v_permlane32_swap_b32 %0, %1" : "+v"(a1), "+v"(b1));
      union { unsigned u[4]; bf16x8 v; } F2;
      F2.u[0] = a0; F2.u[1] = a1; F2.u[2] = b0; F2.u[3] = b1;
      #pragma unroll
      for(int dt=0;dt<8;dt++){
        bf16x8 v2 = *(const bf16x8*)(lds + VOFF + (dt*32+lo5)*144 + 64 + hi*16);
        o[dt] = mfma32(v2, F2.v, o[dt]);
      }
    }
    {
      unsigned a0 = pk[4], b0 = pk[6], a1 = pk[5], b1 = pk[7];
      asm("v_permlane32_swap_b32 %0, %1" : "+v"(a0), "+v"(b0));
      asm("v_permlane32_swap_b32 %0, %1" : "+v"(a1), "+v"(b1));
      union { unsigned u[4]; bf16x8 v; } F3;
      F3.u[0] = a0; F3.u[1] = a1; F3.u[2] = b0; F3.u[3] = b1;
      #pragma unroll
      for(int dt=0;dt<8;dt++){
        bf16x8 v3 = *(const bf16x8*)(lds + VOFF + (dt*32+lo5)*144 + 96 + hi*16);
        o[dt] = mfma32(v3, F3.v, o[dt]);
      }
    }
    __builtin_amdgcn_s_setprio(0);
    __syncthreads();   // all reads done before next stage overwrites
  }

  // write unnormalized partial O (bf16) + (m, lsum)
  unsigned short* pb = (jh ? pO1 : pO0) + ((size_t)nb*HW_ + q0 + lo5)*C_;
  #pragma unroll
  for(int dt=0;dt<8;dt++){
    #pragma unroll
    for(int g=0;g<4;g++){
      int d0 = dt*32 + g*8 + hi*4;
      unsigned short h0 = f2bf(o[dt][4*g]);
      unsigned short h1 = f2bf(o[dt][4*g+1]);
      unsigned short h2 = f2bf(o[dt][4*g+2]);
      unsigned short h3 = f2bf(o[dt][4*g+3]);
      uint2 uo; uo.x = (unsigned)h0 | ((unsigned)h1<<16);
      uo.y = (unsigned)h2 | ((unsigned)h3<<16);
      *(uint2*)(pb + d0) = uo;
    }
  }
  if (l < 32){
    float2 ml; ml.x = m; ml.y = lsum;
    pml[(size_t)jh*32768 + (size_t)nb*HW_ + q0 + lo5] = ml;
  }
}

// ---------------- merge the two j-half partials (in place into pO0 = rest) ----------------
__global__ void k_merge(unsigned short* __restrict__ pO0,
                        const unsigned short* __restrict__ pO1,
                        const float2* __restrict__ pml){
  int t = threadIdx.x;
  int row = blockIdx.x*8 + (t>>5);
  int dn = t & 31;
  float2 ml0 = pml[row], ml1 = pml[32768 + row];
  float mN = fmaxf(ml0.x, ml1.x);
  float a0 = exp2fast(ml0.x - mN), a1 = exp2fast(ml1.x - mN);
  float inv = 1.f/(a0*ml0.y + a1*ml1.y);
  float s0 = a0*inv, s1 = a1*inv;
  size_t off = (size_t)row*256 + dn*8;
  uint4 u0 = *(const uint4*)(pO0 + off);
  uint4 u1 = *(const uint4*)(pO1 + off);
  unsigned r[4];
  unsigned w0[4] = {u0.x, u0.y, u0.z, u0.w};
  unsigned w1[4] = {u1.x, u1.y, u1.z, u1.w};
  #pragma unroll
  for(int q=0;q<4;q++){
    float lo = s0*bf2f((unsigned short)(w0[q]&0xffff)) + s1*bf2f((unsigned short)(w1[q]&0xffff));
    float hi = s0*bf2f((unsigned short)(w0[q]>>16))    + s1*bf2f((unsigned short)(w1[q]>>16));
    r[q] = (unsigned)f2bf(lo) | ((unsigned)f2bf(hi)<<16);
  }
  uint4 ru; ru.x=r[0]; ru.y=r[1]; ru.z=r[2]; ru.w=r[3];
  *(uint4*)(pO0 + off) = ru;
}

// ---------------- output projection + residual (fp32 out) ----------------
__global__ void k_outproj(const unsigned short* __restrict__ wob,
                          const unsigned short* __restrict__ rest,
                          const float* __restrict__ bo, const float* __restrict__ x,
                          float* __restrict__ out){
  int n = blockIdx.z;
  const unsigned short* B = rest + (size_t)n*HW_*C_;
  int t = threadIdx.x, w = t>>6, l = t&63, ri = l&15, k8 = (l>>4)*8;
  int row0 = blockIdx.x*64 + w*16;
  int col0 = blockIdx.y*64;
  f32x4 zero = {0.f,0.f,0.f,0.f};
  f32x4 acc[4] = {zero, zero, zero, zero};
  #pragma unroll
  for(int k=0;k<256;k+=32){
    bf16x8 a = *(const bf16x8*)(wob + (size_t)(row0+ri)*256 + k + k8);
    #pragma unroll
    for(int j=0;j<4;j++){
      bf16x8 b = *(const bf16x8*)(B + (size_t)(col0+j*16+ri)*256 + k + k8);
      acc[j] = mfma16(a,b,acc[j]);
    }
  }
  #pragma unroll
  for(int j=0;j<4;j++){
    #pragma unroll
    for(int r=0;r<4;r++){
      int row = row0 + (l>>4)*4 + r;
      int col = col0 + j*16 + ri;
      size_t idx = ((size_t)n*C_ + row)*HW_ + col;
      out[idx] = acc[j][r] + bo[row] + x[idx];
    }
  }
}

extern "C" void kernel_launch(void* const* d_in, const int* in_sizes, int n_in,
                              void* d_out, int out_size, void* d_ws, size_t ws_size,
                              hipStream_t stream) {
  const float* x   = (const float*)d_in[0];
  const float* lnw = (const float*)d_in[1];
  const float* lnb = (const float*)d_in[2];
  const float* wq  = (const float*)d_in[3];
  const float* bq  = (const float*)d_in[4];
  const float* wk  = (const float*)d_in[5];
  const float* bk  = (const float*)d_in[6];
  const float* wv  = (const float*)d_in[7];
  const float* bv  = (const float*)d_in[8];
  const float* wo  = (const float*)d_in[9];
  const float* bo  = (const float*)d_in[10];
  float* out = (float*)d_out;

  uintptr_t base = (uintptr_t)d_ws;
  float2* part  = (float2*)base;
  float2* stats = (float2*)(base + 16384);
  unsigned short* wqb = (unsigned short*)(base + 16448);
  unsigned short* wkb = wqb + 65536;
  unsigned short* wvb = wqb + 2*65536;
  unsigned short* wob = wqb + 3*65536;
  unsigned short* nx  = wqb + 4*65536;
  const size_t TEN = (size_t)N_*HW_*C_;
  unsigned short* qtb = nx + TEN;
  unsigned short* ktb = qtb + TEN;
  unsigned short* vvb = ktb + TEN;
  unsigned short* pO1 = vvb + TEN;                 // extra 16 MB partial (j-half 1)
  float2* pml = (float2*)(pO1 + TEN);              // 2*32768 float2
  unsigned short* rest = nx;                       // = pO0 (j-half 0), merged in place

  k_cvt<<<dim3(256),256,0,stream>>>(wq, wqb);
  k_cvt<<<dim3(256),256,0,stream>>>(wk, wkb);
  k_cvt<<<dim3(256),256,0,stream>>>(wv, wvb);
  k_cvt<<<dim3(256),256,0,stream>>>(wo, wob);

  k_stats1<<<dim3(2048),256,0,stream>>>(x, part);
  k_stats2<<<dim3(8),256,0,stream>>>(part, stats);
  k_norm<<<dim3(64,4,8),256,0,stream>>>(x, lnw, lnb, stats, nx);

  // Q pre-scaled by log2(e)/16 (softmax runs in base-2), K: [seq][dim]; V: [dim][seq]
  k_gemm<<<dim3(64,4,8),256,0,stream>>>(nx, (long)(HW_*C_), wqb, 0, bq, 0, 0.09016844f, qtb, (long)(HW_*C_), C_);
  k_gemm<<<dim3(64,4,8),256,0,stream>>>(nx, (long)(HW_*C_), wkb, 0, bk, 0, 1.0f, ktb, (long)(HW_*C_), C_);
  k_gemm<<<dim3(4,64,8),256,0,stream>>>(wvb, 0, nx, (long)(HW_*C_), bv, 1, 1.0f, vvb, (long)(C_*HW_), HW_);

  k_attn5<<<dim3(512),256,0,stream>>>(qtb, ktb, vvb, rest, pO1, pml);
  k_merge<<<dim3(4096),256,0,stream>>>(rest, pO1, pml);

  k_outproj<<<dim3(4,64,8),256,0,stream>>>(wob, rest, bo, x, out);
}

// Round 8
// 373.189 us; speedup vs baseline: 1.3041x; 1.3041x over previous
//
#include <hip/hip_runtime.h>
#include <hip/hip_bf16.h>

#define N_ 8
#define C_ 256
#define HW_ 4096
#define CNT_ (C_*HW_)

typedef __attribute__((ext_vector_type(8))) short bf16x8;
typedef __attribute__((ext_vector_type(4))) float f32x4;
typedef __attribute__((ext_vector_type(16))) float f32x16;

__device__ inline float exp2fast(float x){ return __builtin_amdgcn_exp2f(x); }

__device__ inline unsigned short f2bf(float f){
  union{float f; unsigned u;} v; v.f=f;
  unsigned r = v.u + 0x7fff + ((v.u>>16)&1);
  return (unsigned short)(r>>16);
}
__device__ inline float bf2f(unsigned short h){
  union{unsigned u; float f;} v; v.u = ((unsigned)h)<<16; return v.f;
}

__device__ inline f32x4 mfma16(bf16x8 a, bf16x8 b, f32x4 c){
  return __builtin_amdgcn_mfma_f32_16x16x32_bf16(a,b,c,0,0,0);
}
__device__ inline f32x16 mfma32(bf16x8 a, bf16x8 b, f32x16 c){
  return __builtin_amdgcn_mfma_f32_32x32x16_bf16(a,b,c,0,0,0);
}

#define GLL16(gp, lp) __builtin_amdgcn_global_load_lds( \
    (__attribute__((address_space(1))) void*)(gp), \
    (__attribute__((address_space(3))) void*)(lp), 16, 0, 0)

// ---------------- weight convert (fp32 -> bf16) ----------------
__global__ void k_cvt(const float* __restrict__ src, unsigned short* __restrict__ dst){
  int i = blockIdx.x*256 + threadIdx.x;
  dst[i] = f2bf(src[i]);
}

// ---------------- layernorm stats, stage 1 ----------------
__global__ void k_stats1(const float* __restrict__ x, float2* __restrict__ part){
  int n = blockIdx.x >> 8;
  int chunk = blockIdx.x & 255;
  const float4* p = (const float4*)(x + (size_t)n*CNT_ + (size_t)chunk*4096);
  int t = threadIdx.x;
  float s=0.f, s2=0.f;
  #pragma unroll
  for(int i=0;i<4;i++){
    float4 v = p[t + 256*i];
    s  += v.x+v.y+v.z+v.w;
    s2 += v.x*v.x+v.y*v.y+v.z*v.z+v.w*v.w;
  }
  #pragma unroll
  for(int o=32;o;o>>=1){ s += __shfl_down(s,o); s2 += __shfl_down(s2,o); }
  __shared__ float sh[4], sh2[4];
  int lane = t&63, wid = t>>6;
  if(lane==0){ sh[wid]=s; sh2[wid]=s2; }
  __syncthreads();
  if(t==0){
    float2 r; r.x = sh[0]+sh[1]+sh[2]+sh[3]; r.y = sh2[0]+sh2[1]+sh2[2]+sh2[3];
    part[blockIdx.x] = r;
  }
}

// ---------------- layernorm stats, stage 2 ----------------
__global__ void k_stats2(const float2* __restrict__ part, float2* __restrict__ stats){
  int n = blockIdx.x, t = threadIdx.x;
  float2 v = part[n*256 + t];
  float s = v.x, s2 = v.y;
  #pragma unroll
  for(int o=32;o;o>>=1){ s += __shfl_down(s,o); s2 += __shfl_down(s2,o); }
  __shared__ float sh[4], sh2[4];
  int lane = t&63, wid = t>>6;
  if(lane==0){ sh[wid]=s; sh2[wid]=s2; }
  __syncthreads();
  if(t==0){
    s = sh[0]+sh[1]+sh[2]+sh[3];
    s2 = sh2[0]+sh2[1]+sh2[2]+sh2[3];
    float mean = s * (1.f/(float)CNT_);
    float var  = s2 * (1.f/(float)CNT_) - mean*mean;
    float2 r; r.x = mean; r.y = rsqrtf(var + 1e-5f);
    stats[n] = r;
  }
}

// ---------------- normalize + transpose to NHWC bf16 ----------------
__global__ void k_norm(const float* __restrict__ x, const float* __restrict__ lnw,
                       const float* __restrict__ lnb, const float2* __restrict__ stats,
                       unsigned short* __restrict__ nx){
  __shared__ float tile[64][65];
  int n = blockIdx.z, c0 = blockIdx.y*64, p0 = blockIdx.x*64;
  float2 st = stats[n];
  float mu = st.x, rs = st.y;
  int t = threadIdx.x, col = t&63, rw = t>>6;
  #pragma unroll
  for(int pass=0; pass<16; pass++){
    int row = pass*4 + rw;
    size_t gi = (size_t)(c0+row)*HW_ + (p0+col);
    float v = x[(size_t)n*CNT_ + gi];
    tile[row][col] = (v - mu)*rs*lnw[gi] + lnb[gi];
  }
  __syncthreads();
  #pragma unroll
  for(int pass=0; pass<16; pass++){
    int prow = pass*4 + rw;
    nx[((size_t)n*HW_ + p0+prow)*C_ + c0 + col] = f2bf(tile[col][prow]);
  }
}

// ---------------- strip GEMM: D[row][col] = (sum_k A[row][k]*B[col][k] + bias)*scale ----
__global__ void k_gemm(const unsigned short* __restrict__ Abase, long strideA,
                       const unsigned short* __restrict__ Bbase, long strideB,
                       const float* __restrict__ bias, int bias_row, float scale,
                       unsigned short* __restrict__ Out, long strideO, int ldo){
  int n = blockIdx.z;
  const unsigned short* A = Abase + (size_t)n*strideA;
  const unsigned short* B = Bbase + (size_t)n*strideB;
  unsigned short* O = Out + (size_t)n*strideO;
  int t = threadIdx.x, w = t>>6, l = t&63, ri = l&15, k8 = (l>>4)*8;
  int row0 = blockIdx.x*64 + w*16;
  int col0 = blockIdx.y*64;
  f32x4 zero = {0.f,0.f,0.f,0.f};
  f32x4 acc[4] = {zero, zero, zero, zero};
  #pragma unroll
  for(int k=0;k<256;k+=32){
    bf16x8 a = *(const bf16x8*)(A + (size_t)(row0+ri)*256 + k + k8);
    #pragma unroll
    for(int j=0;j<4;j++){
      bf16x8 b = *(const bf16x8*)(B + (size_t)(col0+j*16+ri)*256 + k + k8);
      acc[j] = mfma16(a,b,acc[j]);
    }
  }
  #pragma unroll
  for(int j=0;j<4;j++){
    #pragma unroll
    for(int r=0;r<4;r++){
      int row = row0 + (l>>4)*4 + r;
      int col = col0 + j*16 + ri;
      float d = (acc[j][r] + (bias_row ? bias[row] : bias[col]))*scale;
      O[(size_t)row*ldo + col] = f2bf(d);
    }
  }
}

// ---------------- flash attention: dbuf LDS, issue-early stage, 1 barrier/iter ----------------
// 512 blocks x 256 threads. Block = (batch nb, q-tile of 128, j-half of 2048).
// Wave w owns q-strip of 32. Per buf: K[32][512B] XOR-swizzled (16 KB) + V[256][80B] (20 KB).
// 2 bufs = 72 KB -> 2 blocks/CU. Next tile's GLLs issued BEFORE compute; the single
// end-of-iter __syncthreads (vmcnt0+barrier) drains loads hidden under ~2500 cyc of compute.
__device__ inline void stage_KV(const char* kb, const char* vb, char* ldsbuf,
                                int w, int l, int j0){
  int hi = l>>5, lo5 = l&31;
  #pragma unroll
  for(int k=0;k<4;k++){
    int i = w*4+k;
    int row = 2*i + hi;
    GLL16(kb + ((size_t)(j0+row)<<9) + (((lo5^row)&31)<<4), ldsbuf + (i<<10));
  }
  #pragma unroll
  for(int k=0;k<5;k++){
    int g = w*5+k;
    int c = g*64 + l;
    int d = c/5; int sg = c - d*5; sg = (sg==4)?0:sg;
    GLL16(vb + ((size_t)d<<13) + ((size_t)j0<<1) + (sg<<4), ldsbuf + 16384 + (g<<10));
  }
}

__global__ __launch_bounds__(256, 2) void k_attn6(const unsigned short* __restrict__ qt,
                                                  const unsigned short* __restrict__ kt,
                                                  const unsigned short* __restrict__ vv,
                                                  unsigned short* __restrict__ pO0,
                                                  unsigned short* __restrict__ pO1,
                                                  float2* __restrict__ pml){
  __shared__ __align__(16) char lds[73728];     // 2 x (16 KB K + 20 KB V)
  int t = threadIdx.x, w = t>>6, l = t&63, hi = l>>5, lo5 = l&31;
  int nb = blockIdx.x & 7, rem = blockIdx.x >> 3;
  int qb = rem >> 1, jh = rem & 1;
  int q0 = qb*128 + w*32;
  const char* kb = (const char*)(kt + (size_t)nb*HW_*C_);
  const char* vb = (const char*)(vv + (size_t)nb*C_*HW_);
  const char* qp = (const char*)(qt + (size_t)nb*HW_*C_);
  int jbase = jh*2048;

  bf16x8 qf[16];
  #pragma unroll
  for(int ds=0; ds<16; ds++)
    qf[ds] = *(const bf16x8*)(qp + ((size_t)(q0+lo5)<<9) + ds*32 + hi*16);

  f32x16 o[8];
  #pragma unroll
  for(int dt=0;dt<8;dt++){
    #pragma unroll
    for(int r=0;r<16;r++) o[dt][r]=0.f;
  }
  float m = -1e30f, lsum = 0.f;

  // prologue: stage tile 0 into buf 0, wait
  stage_KV(kb, vb, lds, w, l, jbase);
  __syncthreads();

  for(int it=0; it<64; ++it){
    int cur = it & 1;
    char* bufc = lds + cur*36864;
    // issue next tile's loads early (dest = other buffer, free since last barrier)
    if (it < 63) stage_KV(kb, vb, lds + (cur^1)*36864, w, l, jbase + (it+1)*32);

    // QK^T: S[j][q], lane holds q=lo5 (swapped operands)
    f32x16 S;
    #pragma unroll
    for(int r=0;r<16;r++) S[r]=0.f;
    __builtin_amdgcn_s_setprio(1);
    #pragma unroll
    for(int ds=0; ds<16; ds++){
      bf16x8 kf = *(const bf16x8*)(bufc + (lo5<<9) + ((((ds<<1)|hi)^lo5)<<4));
      S = mfma32(kf, qf[ds], S);
    }
    __builtin_amdgcn_s_setprio(0);

    // online softmax (base-2; Q pre-scaled by log2e/16); balanced max tree
    float p0 = fmaxf(S[0],S[8]),  p1 = fmaxf(S[1],S[9]);
    float p2 = fmaxf(S[2],S[10]), p3 = fmaxf(S[3],S[11]);
    float p4 = fmaxf(S[4],S[12]), p5 = fmaxf(S[5],S[13]);
    float p6 = fmaxf(S[6],S[14]), p7 = fmaxf(S[7],S[15]);
    p0 = fmaxf(p0,p4); p1 = fmaxf(p1,p5); p2 = fmaxf(p2,p6); p3 = fmaxf(p3,p7);
    float mx = fmaxf(fmaxf(p0,p1), fmaxf(p2,p3));
    { float mA = mx, mB = mx;
      asm("v_permlane32_swap_b32 %0, %1" : "+v"(mA), "+v"(mB));
      mx = fmaxf(mA, mB); }
    if (!__all(mx <= m + 11.5f)){
      float mn = fmaxf(m, mx);
      float al = exp2fast(m - mn);
      lsum *= al;
      #pragma unroll
      for(int dt=0;dt<8;dt++) o[dt] = o[dt] * al;
      m = mn;
    }
    unsigned pk[8];
    float rs = 0.f;
    #pragma unroll
    for(int tt=0;tt<8;tt++){
      float pa = exp2fast(S[2*tt]-m), pb = exp2fast(S[2*tt+1]-m);
      rs += pa + pb;
      unsigned pr;
      asm("v_cvt_pk_bf16_f32 %0, %1, %2" : "=v"(pr) : "v"(pa), "v"(pb));
      pk[tt] = pr;
    }
    { float rA = rs, rB = rs;
      asm("v_permlane32_swap_b32 %0, %1" : "+v"(rA), "+v"(rB));
      lsum += rA + rB; }

    // PV: O^T[d][q] += V[d][j] * P[q][j]; F-fragments via permlane32_swap
    __builtin_amdgcn_s_setprio(1);
    {
      unsigned a0 = pk[0], b0 = pk[2], a1 = pk[1], b1 = pk[3];
      asm("v_permlane32_swap_b32 %0, %1" : "+v"(a0), "+v"(b0));
      asm("v_permlane32_swap_b32 %0, %1" : "+v"(a1), "+v"(b1));
      union { unsigned u[4]; bf16x8 v; } F0;
      F0.u[0] = a0; F0.u[1] = a1; F0.u[2] = b0; F0.u[3] = b1;
      #pragma unroll
      for(int dt=0;dt<8;dt++){
        bf16x8 v0 = *(const bf16x8*)(bufc + 16384 + (dt*32+lo5)*80 + hi*16);
        o[dt] = mfma32(v0, F0.v, o[dt]);
      }
    }
    {
      unsigned a0 = pk[4], b0 = pk[6], a1 = pk[5], b1 = pk[7];
      asm("v_permlane32_swap_b32 %0, %1" : "+v"(a0), "+v"(b0));
      asm("v_permlane32_swap_b32 %0, %1" : "+v"(a1), "+v"(b1));
      union { unsigned u[4]; bf16x8 v; } F1;
      F1.u[0] = a0; F1.u[1] = a1; F1.u[2] = b0; F1.u[3] = b1;
      #pragma unroll
      for(int dt=0;dt<8;dt++){
        bf16x8 v1 = *(const bf16x8*)(bufc + 16384 + (dt*32+lo5)*80 + 32 + hi*16);
        o[dt] = mfma32(v1, F1.v, o[dt]);
      }
    }
    __builtin_amdgcn_s_setprio(0);
    // single barrier: drains this iter's prefetch (hidden under compute) and
    // guarantees all waves finished reading bufc before it's overwritten next iter
    __syncthreads();
  }

  // write unnormalized partial O (bf16) + (m, lsum)
  unsigned short* pb = (jh ? pO1 : pO0) + ((size_t)nb*HW_ + q0 + lo5)*C_;
  #pragma unroll
  for(int dt=0;dt<8;dt++){
    #pragma unroll
    for(int g=0;g<4;g++){
      int d0 = dt*32 + g*8 + hi*4;
      unsigned short h0 = f2bf(o[dt][4*g]);
      unsigned short h1 = f2bf(o[dt][4*g+1]);
      unsigned short h2 = f2bf(o[dt][4*g+2]);
      unsigned short h3 = f2bf(o[dt][4*g+3]);
      uint2 uo; uo.x = (unsigned)h0 | ((unsigned)h1<<16);
      uo.y = (unsigned)h2 | ((unsigned)h3<<16);
      *(uint2*)(pb + d0) = uo;
    }
  }
  if (l < 32){
    float2 ml; ml.x = m; ml.y = lsum;
    pml[(size_t)jh*32768 + (size_t)nb*HW_ + q0 + lo5] = ml;
  }
}

// ---------------- merge the two j-half partials (in place into pO0 = rest) ----------------
__global__ void k_merge(unsigned short* __restrict__ pO0,
                        const unsigned short* __restrict__ pO1,
                        const float2* __restrict__ pml){
  int t = threadIdx.x;
  int row = blockIdx.x*8 + (t>>5);
  int dn = t & 31;
  float2 ml0 = pml[row], ml1 = pml[32768 + row];
  float mN = fmaxf(ml0.x, ml1.x);
  float a0 = exp2fast(ml0.x - mN), a1 = exp2fast(ml1.x - mN);
  float inv = 1.f/(a0*ml0.y + a1*ml1.y);
  float s0 = a0*inv, s1 = a1*inv;
  size_t off = (size_t)row*256 + dn*8;
  uint4 u0 = *(const uint4*)(pO0 + off);
  uint4 u1 = *(const uint4*)(pO1 + off);
  unsigned r[4];
  unsigned w0[4] = {u0.x, u0.y, u0.z, u0.w};
  unsigned w1[4] = {u1.x, u1.y, u1.z, u1.w};
  #pragma unroll
  for(int q=0;q<4;q++){
    float lo = s0*bf2f((unsigned short)(w0[q]&0xffff)) + s1*bf2f((unsigned short)(w1[q]&0xffff));
    float hi = s0*bf2f((unsigned short)(w0[q]>>16))    + s1*bf2f((unsigned short)(w1[q]>>16));
    r[q] = (unsigned)f2bf(lo) | ((unsigned)f2bf(hi)<<16);
  }
  uint4 ru; ru.x=r[0]; ru.y=r[1]; ru.z=r[2]; ru.w=r[3];
  *(uint4*)(pO0 + off) = ru;
}

// ---------------- output projection + residual (fp32 out) ----------------
__global__ void k_outproj(const unsigned short* __restrict__ wob,
                          const unsigned short* __restrict__ rest,
                          const float* __restrict__ bo, const float* __restrict__ x,
                          float* __restrict__ out){
  int n = blockIdx.z;
  const unsigned short* B = rest + (size_t)n*HW_*C_;
  int t = threadIdx.x, w = t>>6, l = t&63, ri = l&15, k8 = (l>>4)*8;
  int row0 = blockIdx.x*64 + w*16;
  int col0 = blockIdx.y*64;
  f32x4 zero = {0.f,0.f,0.f,0.f};
  f32x4 acc[4] = {zero, zero, zero, zero};
  #pragma unroll
  for(int k=0;k<256;k+=32){
    bf16x8 a = *(const bf16x8*)(wob + (size_t)(row0+ri)*256 + k + k8);
    #pragma unroll
    for(int j=0;j<4;j++){
      bf16x8 b = *(const bf16x8*)(B + (size_t)(col0+j*16+ri)*256 + k + k8);
      acc[j] = mfma16(a,b,acc[j]);
    }
  }
  #pragma unroll
  for(int j=0;j<4;j++){
    #pragma unroll
    for(int r=0;r<4;r++){
      int row = row0 + (l>>4)*4 + r;
      int col = col0 + j*16 + ri;
      size_t idx = ((size_t)n*C_ + row)*HW_ + col;
      out[idx] = acc[j][r] + bo[row] + x[idx];
    }
  }
}

extern "C" void kernel_launch(void* const* d_in, const int* in_sizes, int n_in,
                              void* d_out, int out_size, void* d_ws, size_t ws_size,
                              hipStream_t stream) {
  const float* x   = (const float*)d_in[0];
  const float* lnw = (const float*)d_in[1];
  const float* lnb = (const float*)d_in[2];
  const float* wq  = (const float*)d_in[3];
  const float* bq  = (const float*)d_in[4];
  const float* wk  = (const float*)d_in[5];
  const float* bk  = (const float*)d_in[6];
  const float* wv  = (const float*)d_in[7];
  const float* bv  = (const float*)d_in[8];
  const float* wo  = (const float*)d_in[9];
  const float* bo  = (const float*)d_in[10];
  float* out = (float*)d_out;

  uintptr_t base = (uintptr_t)d_ws;
  float2* part  = (float2*)base;
  float2* stats = (float2*)(base + 16384);
  unsigned short* wqb = (unsigned short*)(base + 16448);
  unsigned short* wkb = wqb + 65536;
  unsigned short* wvb = wqb + 2*65536;
  unsigned short* wob = wqb + 3*65536;
  unsigned short* nx  = wqb + 4*65536;
  const size_t TEN = (size_t)N_*HW_*C_;
  unsigned short* qtb = nx + TEN;
  unsigned short* ktb = qtb + TEN;
  unsigned short* vvb = ktb + TEN;
  unsigned short* pO1 = vvb + TEN;                 // extra 16 MB partial (j-half 1)
  float2* pml = (float2*)(pO1 + TEN);              // 2*32768 float2
  unsigned short* rest = nx;                       // = pO0 (j-half 0), merged in place

  k_cvt<<<dim3(256),256,0,stream>>>(wq, wqb);
  k_cvt<<<dim3(256),256,0,stream>>>(wk, wkb);
  k_cvt<<<dim3(256),256,0,stream>>>(wv, wvb);
  k_cvt<<<dim3(256),256,0,stream>>>(wo, wob);

  k_stats1<<<dim3(2048),256,0,stream>>>(x, part);
  k_stats2<<<dim3(8),256,0,stream>>>(part, stats);
  k_norm<<<dim3(64,4,8),256,0,stream>>>(x, lnw, lnb, stats, nx);

  // Q pre-scaled by log2(e)/16 (softmax runs in base-2), K: [seq][dim]; V: [dim][seq]
  k_gemm<<<dim3(64,4,8),256,0,stream>>>(nx, (long)(HW_*C_), wqb, 0, bq, 0, 0.09016844f, qtb, (long)(HW_*C_), C_);
  k_gemm<<<dim3(64,4,8),256,0,stream>>>(nx, (long)(HW_*C_), wkb, 0, bk, 0, 1.0f, ktb, (long)(HW_*C_), C_);
  k_gemm<<<dim3(4,64,8),256,0,stream>>>(wvb, 0, nx, (long)(HW_*C_), bv, 1, 1.0f, vvb, (long)(C_*HW_), HW_);

  k_attn6<<<dim3(512),256,0,stream>>>(qtb, ktb, vvb, rest, pO1, pml);
  k_merge<<<dim3(4096),256,0,stream>>>(rest, pO1, pml);

  k_outproj<<<dim3(4,64,8),256,0,stream>>>(wob, rest, bo, x, out);
}

// Round 9
// 273.332 us; speedup vs baseline: 1.7805x; 1.3653x over previous
//
#include <hip/hip_runtime.h>
#include <hip/hip_bf16.h>

#define N_ 8
#define C_ 256
#define HW_ 4096
#define CNT_ (C_*HW_)

typedef __attribute__((ext_vector_type(8))) short bf16x8;
typedef __attribute__((ext_vector_type(4))) float f32x4;
typedef __attribute__((ext_vector_type(16))) float f32x16;

__device__ inline float exp2fast(float x){ return __builtin_amdgcn_exp2f(x); }

__device__ inline unsigned short f2bf(float f){
  union{float f; unsigned u;} v; v.f=f;
  unsigned r = v.u + 0x7fff + ((v.u>>16)&1);
  return (unsigned short)(r>>16);
}
__device__ inline float bf2f(unsigned short h){
  union{unsigned u; float f;} v; v.u = ((unsigned)h)<<16; return v.f;
}

__device__ inline f32x4 mfma16(bf16x8 a, bf16x8 b, f32x4 c){
  return __builtin_amdgcn_mfma_f32_16x16x32_bf16(a,b,c,0,0,0);
}
__device__ inline f32x16 mfma32(bf16x8 a, bf16x8 b, f32x16 c){
  return __builtin_amdgcn_mfma_f32_32x32x16_bf16(a,b,c,0,0,0);
}

#define GLL16(gp, lp) __builtin_amdgcn_global_load_lds( \
    (__attribute__((address_space(1))) void*)(gp), \
    (__attribute__((address_space(3))) void*)(lp), 16, 0, 0)

// ---------------- weight convert (fp32 -> bf16) ----------------
__global__ void k_cvt(const float* __restrict__ src, unsigned short* __restrict__ dst){
  int i = blockIdx.x*256 + threadIdx.x;
  dst[i] = f2bf(src[i]);
}

// ---------------- layernorm stats, stage 1 ----------------
__global__ void k_stats1(const float* __restrict__ x, float2* __restrict__ part){
  int n = blockIdx.x >> 8;
  int chunk = blockIdx.x & 255;
  const float4* p = (const float4*)(x + (size_t)n*CNT_ + (size_t)chunk*4096);
  int t = threadIdx.x;
  float s=0.f, s2=0.f;
  #pragma unroll
  for(int i=0;i<4;i++){
    float4 v = p[t + 256*i];
    s  += v.x+v.y+v.z+v.w;
    s2 += v.x*v.x+v.y*v.y+v.z*v.z+v.w*v.w;
  }
  #pragma unroll
  for(int o=32;o;o>>=1){ s += __shfl_down(s,o); s2 += __shfl_down(s2,o); }
  __shared__ float sh[4], sh2[4];
  int lane = t&63, wid = t>>6;
  if(lane==0){ sh[wid]=s; sh2[wid]=s2; }
  __syncthreads();
  if(t==0){
    float2 r; r.x = sh[0]+sh[1]+sh[2]+sh[3]; r.y = sh2[0]+sh2[1]+sh2[2]+sh2[3];
    part[blockIdx.x] = r;
  }
}

// ---------------- layernorm stats, stage 2 ----------------
__global__ void k_stats2(const float2* __restrict__ part, float2* __restrict__ stats){
  int n = blockIdx.x, t = threadIdx.x;
  float2 v = part[n*256 + t];
  float s = v.x, s2 = v.y;
  #pragma unroll
  for(int o=32;o;o>>=1){ s += __shfl_down(s,o); s2 += __shfl_down(s2,o); }
  __shared__ float sh[4], sh2[4];
  int lane = t&63, wid = t>>6;
  if(lane==0){ sh[wid]=s; sh2[wid]=s2; }
  __syncthreads();
  if(t==0){
    s = sh[0]+sh[1]+sh[2]+sh[3];
    s2 = sh2[0]+sh2[1]+sh2[2]+sh2[3];
    float mean = s * (1.f/(float)CNT_);
    float var  = s2 * (1.f/(float)CNT_) - mean*mean;
    float2 r; r.x = mean; r.y = rsqrtf(var + 1e-5f);
    stats[n] = r;
  }
}

// ---------------- normalize + transpose to NHWC bf16 ----------------
__global__ void k_norm(const float* __restrict__ x, const float* __restrict__ lnw,
                       const float* __restrict__ lnb, const float2* __restrict__ stats,
                       unsigned short* __restrict__ nx){
  __shared__ float tile[64][65];
  int n = blockIdx.z, c0 = blockIdx.y*64, p0 = blockIdx.x*64;
  float2 st = stats[n];
  float mu = st.x, rs = st.y;
  int t = threadIdx.x, col = t&63, rw = t>>6;
  #pragma unroll
  for(int pass=0; pass<16; pass++){
    int row = pass*4 + rw;
    size_t gi = (size_t)(c0+row)*HW_ + (p0+col);
    float v = x[(size_t)n*CNT_ + gi];
    tile[row][col] = (v - mu)*rs*lnw[gi] + lnb[gi];
  }
  __syncthreads();
  #pragma unroll
  for(int pass=0; pass<16; pass++){
    int prow = pass*4 + rw;
    nx[((size_t)n*HW_ + p0+prow)*C_ + c0 + col] = f2bf(tile[col][prow]);
  }
}

// ---------------- 128x128-tile B^T GEMM, LDS-staged (dbuf, issue-early) ----------------
// D[row][col] = sum_k A[row][k]*B[col][k]; K=256, BK=64, 256 thr (2x2 waves of 64x64).
// LDS per buf: A[128][64] + B[128][64] bf16, XOR-slot swizzled (2-way banks on ds_read_b128).
// BIAS_ROW: bias indexed by row (V/outproj) vs col (Q/K). OUTF32: fp32 out + residual.
__device__ inline void g2_stage(const char* A, const char* B, char* buf,
                                int w, int r8, int s8, int i0, int c0, int kb0){
  int sl = (s8 ^ (r8&7)) << 4;
  #pragma unroll
  for(int q=0;q<4;q++){
    int row = w*32 + q*8 + r8;
    GLL16(A + (size_t)(i0+row)*512 + kb0 + sl, buf + w*4096 + q*1024);
    GLL16(B + (size_t)(c0+row)*512 + kb0 + sl, buf + 16384 + w*4096 + q*1024);
  }
}

template<int BIAS_ROW, int OUTF32>
__global__ __launch_bounds__(256, 2) void k_gemm2(
    const unsigned short* __restrict__ Ab, long sA,
    const unsigned short* __restrict__ Bb, long sB,
    const float* __restrict__ bias, float scale,
    unsigned short* __restrict__ Outb, long sO, int ldo,
    float* __restrict__ foutb, const float* __restrict__ xres){
  __shared__ __align__(16) char lds[65536];
  int n = blockIdx.z;
  const char* A = (const char*)(Ab + (size_t)n*sA);
  const char* B = (const char*)(Bb + (size_t)n*sB);
  int t = threadIdx.x, w = t>>6, l = t&63;
  int wr = w>>1, wc = w&1, ri = l&15, kq = l>>4;
  int r8 = l>>3, s8 = l&7;
  int i0 = blockIdx.x*128, c0 = blockIdx.y*128;

  f32x4 acc[4][4];
  #pragma unroll
  for(int m=0;m<4;m++)
    #pragma unroll
    for(int nn=0;nn<4;nn++)
      #pragma unroll
      for(int r=0;r<4;r++) acc[m][nn][r] = 0.f;

  g2_stage(A, B, lds, w, r8, s8, i0, c0, 0);
  __syncthreads();

  for(int kt=0; kt<4; ++kt){
    char* buf = lds + (kt&1)*32768;
    if (kt < 3) g2_stage(A, B, lds + ((kt&1)^1)*32768, w, r8, s8, i0, c0, (kt+1)*128);
    __builtin_amdgcn_s_setprio(1);
    #pragma unroll
    for(int kc=0;kc<2;kc++){
      bf16x8 af[4], bfv[4];
      #pragma unroll
      for(int m=0;m<4;m++){
        int row = wr*64 + m*16 + ri;
        af[m] = *(const bf16x8*)(buf + row*128 + ((((kc<<2)|kq) ^ (row&7))<<4));
      }
      #pragma unroll
      for(int nn=0;nn<4;nn++){
        int row = wc*64 + nn*16 + ri;
        bfv[nn] = *(const bf16x8*)(buf + 16384 + row*128 + ((((kc<<2)|kq) ^ (row&7))<<4));
      }
      #pragma unroll
      for(int m=0;m<4;m++)
        #pragma unroll
        for(int nn=0;nn<4;nn++)
          acc[m][nn] = mfma16(af[m], bfv[nn], acc[m][nn]);
    }
    __builtin_amdgcn_s_setprio(0);
    __syncthreads();
  }

  if (OUTF32){
    float* fout = foutb + (size_t)n*sO;
    const float* xr = xres + (size_t)n*sO;
    #pragma unroll
    for(int m=0;m<4;m++){
      #pragma unroll
      for(int nn=0;nn<4;nn++){
        #pragma unroll
        for(int r=0;r<4;r++){
          int row = i0 + wr*64 + m*16 + kq*4 + r;
          int col = c0 + wc*64 + nn*16 + ri;
          size_t idx = (size_t)row*ldo + col;
          fout[idx] = acc[m][nn][r] + bias[row] + xr[idx];
        }
      }
    }
  } else {
    unsigned short* O = Outb + (size_t)n*sO;
    #pragma unroll
    for(int m=0;m<4;m++){
      #pragma unroll
      for(int nn=0;nn<4;nn++){
        #pragma unroll
        for(int r=0;r<4;r++){
          int row = i0 + wr*64 + m*16 + kq*4 + r;
          int col = c0 + wc*64 + nn*16 + ri;
          float d = (acc[m][nn][r] + bias[BIAS_ROW ? row : col])*scale;
          O[(size_t)row*ldo + col] = f2bf(d);
        }
      }
    }
  }
}

// ---------------- flash attention: dbuf LDS, issue-early stage, 1 barrier/iter ----------------
__device__ inline void stage_KV(const char* kb, const char* vb, char* ldsbuf,
                                int w, int l, int j0){
  int hi = l>>5, lo5 = l&31;
  #pragma unroll
  for(int k=0;k<4;k++){
    int i = w*4+k;
    int row = 2*i + hi;
    GLL16(kb + ((size_t)(j0+row)<<9) + (((lo5^row)&31)<<4), ldsbuf + (i<<10));
  }
  #pragma unroll
  for(int k=0;k<5;k++){
    int g = w*5+k;
    int c = g*64 + l;
    int d = c/5; int sg = c - d*5; sg = (sg==4)?0:sg;
    GLL16(vb + ((size_t)d<<13) + ((size_t)j0<<1) + (sg<<4), ldsbuf + 16384 + (g<<10));
  }
}

__global__ __launch_bounds__(256, 2) void k_attn6(const unsigned short* __restrict__ qt,
                                                  const unsigned short* __restrict__ kt,
                                                  const unsigned short* __restrict__ vv,
                                                  unsigned short* __restrict__ pO0,
                                                  unsigned short* __restrict__ pO1,
                                                  float2* __restrict__ pml){
  __shared__ __align__(16) char lds[73728];     // 2 x (16 KB K + 20 KB V)
  int t = threadIdx.x, w = t>>6, l = t&63, hi = l>>5, lo5 = l&31;
  int nb = blockIdx.x & 7, rem = blockIdx.x >> 3;
  int qb = rem >> 1, jh = rem & 1;
  int q0 = qb*128 + w*32;
  const char* kb = (const char*)(kt + (size_t)nb*HW_*C_);
  const char* vb = (const char*)(vv + (size_t)nb*C_*HW_);
  const char* qp = (const char*)(qt + (size_t)nb*HW_*C_);
  int jbase = jh*2048;

  bf16x8 qf[16];
  #pragma unroll
  for(int ds=0; ds<16; ds++)
    qf[ds] = *(const bf16x8*)(qp + ((size_t)(q0+lo5)<<9) + ds*32 + hi*16);

  f32x16 o[8];
  #pragma unroll
  for(int dt=0;dt<8;dt++){
    #pragma unroll
    for(int r=0;r<16;r++) o[dt][r]=0.f;
  }
  float m = -1e30f, lsum = 0.f;

  stage_KV(kb, vb, lds, w, l, jbase);
  __syncthreads();

  for(int it=0; it<64; ++it){
    int cur = it & 1;
    char* bufc = lds + cur*36864;
    if (it < 63) stage_KV(kb, vb, lds + (cur^1)*36864, w, l, jbase + (it+1)*32);

    f32x16 S;
    #pragma unroll
    for(int r=0;r<16;r++) S[r]=0.f;
    __builtin_amdgcn_s_setprio(1);
    #pragma unroll
    for(int ds=0; ds<16; ds++){
      bf16x8 kf = *(const bf16x8*)(bufc + (lo5<<9) + ((((ds<<1)|hi)^lo5)<<4));
      S = mfma32(kf, qf[ds], S);
    }
    __builtin_amdgcn_s_setprio(0);

    float p0 = fmaxf(S[0],S[8]),  p1 = fmaxf(S[1],S[9]);
    float p2 = fmaxf(S[2],S[10]), p3 = fmaxf(S[3],S[11]);
    float p4 = fmaxf(S[4],S[12]), p5 = fmaxf(S[5],S[13]);
    float p6 = fmaxf(S[6],S[14]), p7 = fmaxf(S[7],S[15]);
    p0 = fmaxf(p0,p4); p1 = fmaxf(p1,p5); p2 = fmaxf(p2,p6); p3 = fmaxf(p3,p7);
    float mx = fmaxf(fmaxf(p0,p1), fmaxf(p2,p3));
    { float mA = mx, mB = mx;
      asm("v_permlane32_swap_b32 %0, %1" : "+v"(mA), "+v"(mB));
      mx = fmaxf(mA, mB); }
    if (!__all(mx <= m + 11.5f)){
      float mn = fmaxf(m, mx);
      float al = exp2fast(m - mn);
      lsum *= al;
      #pragma unroll
      for(int dt=0;dt<8;dt++) o[dt] = o[dt] * al;
      m = mn;
    }
    unsigned pk[8];
    float rs = 0.f;
    #pragma unroll
    for(int tt=0;tt<8;tt++){
      float pa = exp2fast(S[2*tt]-m), pb = exp2fast(S[2*tt+1]-m);
      rs += pa + pb;
      unsigned pr;
      asm("v_cvt_pk_bf16_f32 %0, %1, %2" : "=v"(pr) : "v"(pa), "v"(pb));
      pk[tt] = pr;
    }
    { float rA = rs, rB = rs;
      asm("v_permlane32_swap_b32 %0, %1" : "+v"(rA), "+v"(rB));
      lsum += rA + rB; }

    __builtin_amdgcn_s_setprio(1);
    {
      unsigned a0 = pk[0], b0 = pk[2], a1 = pk[1], b1 = pk[3];
      asm("v_permlane32_swap_b32 %0, %1" : "+v"(a0), "+v"(b0));
      asm("v_permlane32_swap_b32 %0, %1" : "+v"(a1), "+v"(b1));
      union { unsigned u[4]; bf16x8 v; } F0;
      F0.u[0] = a0; F0.u[1] = a1; F0.u[2] = b0; F0.u[3] = b1;
      #pragma unroll
      for(int dt=0;dt<8;dt++){
        bf16x8 v0 = *(const bf16x8*)(bufc + 16384 + (dt*32+lo5)*80 + hi*16);
        o[dt] = mfma32(v0, F0.v, o[dt]);
      }
    }
    {
      unsigned a0 = pk[4], b0 = pk[6], a1 = pk[5], b1 = pk[7];
      asm("v_permlane32_swap_b32 %0, %1" : "+v"(a0), "+v"(b0));
      asm("v_permlane32_swap_b32 %0, %1" : "+v"(a1), "+v"(b1));
      union { unsigned u[4]; bf16x8 v; } F1;
      F1.u[0] = a0; F1.u[1] = a1; F1.u[2] = b0; F1.u[3] = b1;
      #pragma unroll
      for(int dt=0;dt<8;dt++){
        bf16x8 v1 = *(const bf16x8*)(bufc + 16384 + (dt*32+lo5)*80 + 32 + hi*16);
        o[dt] = mfma32(v1, F1.v, o[dt]);
      }
    }
    __builtin_amdgcn_s_setprio(0);
    __syncthreads();
  }

  unsigned short* pb = (jh ? pO1 : pO0) + ((size_t)nb*HW_ + q0 + lo5)*C_;
  #pragma unroll
  for(int dt=0;dt<8;dt++){
    #pragma unroll
    for(int g=0;g<4;g++){
      int d0 = dt*32 + g*8 + hi*4;
      unsigned short h0 = f2bf(o[dt][4*g]);
      unsigned short h1 = f2bf(o[dt][4*g+1]);
      unsigned short h2 = f2bf(o[dt][4*g+2]);
      unsigned short h3 = f2bf(o[dt][4*g+3]);
      uint2 uo; uo.x = (unsigned)h0 | ((unsigned)h1<<16);
      uo.y = (unsigned)h2 | ((unsigned)h3<<16);
      *(uint2*)(pb + d0) = uo;
    }
  }
  if (l < 32){
    float2 ml; ml.x = m; ml.y = lsum;
    pml[(size_t)jh*32768 + (size_t)nb*HW_ + q0 + lo5] = ml;
  }
}

// ---------------- merge the two j-half partials (in place into pO0 = rest) ----------------
__global__ void k_merge(unsigned short* __restrict__ pO0,
                        const unsigned short* __restrict__ pO1,
                        const float2* __restrict__ pml){
  int t = threadIdx.x;
  int row = blockIdx.x*8 + (t>>5);
  int dn = t & 31;
  float2 ml0 = pml[row], ml1 = pml[32768 + row];
  float mN = fmaxf(ml0.x, ml1.x);
  float a0 = exp2fast(ml0.x - mN), a1 = exp2fast(ml1.x - mN);
  float inv = 1.f/(a0*ml0.y + a1*ml1.y);
  float s0 = a0*inv, s1 = a1*inv;
  size_t off = (size_t)row*256 + dn*8;
  uint4 u0 = *(const uint4*)(pO0 + off);
  uint4 u1 = *(const uint4*)(pO1 + off);
  unsigned r[4];
  unsigned w0[4] = {u0.x, u0.y, u0.z, u0.w};
  unsigned w1[4] = {u1.x, u1.y, u1.z, u1.w};
  #pragma unroll
  for(int q=0;q<4;q++){
    float lo = s0*bf2f((unsigned short)(w0[q]&0xffff)) + s1*bf2f((unsigned short)(w1[q]&0xffff));
    float hi = s0*bf2f((unsigned short)(w0[q]>>16))    + s1*bf2f((unsigned short)(w1[q]>>16));
    r[q] = (unsigned)f2bf(lo) | ((unsigned)f2bf(hi)<<16);
  }
  uint4 ru; ru.x=r[0]; ru.y=r[1]; ru.z=r[2]; ru.w=r[3];
  *(uint4*)(pO0 + off) = ru;
}

extern "C" void kernel_launch(void* const* d_in, const int* in_sizes, int n_in,
                              void* d_out, int out_size, void* d_ws, size_t ws_size,
                              hipStream_t stream) {
  const float* x   = (const float*)d_in[0];
  const float* lnw = (const float*)d_in[1];
  const float* lnb = (const float*)d_in[2];
  const float* wq  = (const float*)d_in[3];
  const float* bq  = (const float*)d_in[4];
  const float* wk  = (const float*)d_in[5];
  const float* bk  = (const float*)d_in[6];
  const float* wv  = (const float*)d_in[7];
  const float* bv  = (const float*)d_in[8];
  const float* wo  = (const float*)d_in[9];
  const float* bo  = (const float*)d_in[10];
  float* out = (float*)d_out;

  uintptr_t base = (uintptr_t)d_ws;
  float2* part  = (float2*)base;
  float2* stats = (float2*)(base + 16384);
  unsigned short* wqb = (unsigned short*)(base + 16448);
  unsigned short* wkb = wqb + 65536;
  unsigned short* wvb = wqb + 2*65536;
  unsigned short* wob = wqb + 3*65536;
  unsigned short* nx  = wqb + 4*65536;
  const size_t TEN = (size_t)N_*HW_*C_;
  unsigned short* qtb = nx + TEN;
  unsigned short* ktb = qtb + TEN;
  unsigned short* vvb = ktb + TEN;
  unsigned short* pO1 = vvb + TEN;                 // extra 16 MB partial (j-half 1)
  float2* pml = (float2*)(pO1 + TEN);              // 2*32768 float2
  unsigned short* rest = nx;                       // = pO0 (j-half 0), merged in place

  k_cvt<<<dim3(256),256,0,stream>>>(wq, wqb);
  k_cvt<<<dim3(256),256,0,stream>>>(wk, wkb);
  k_cvt<<<dim3(256),256,0,stream>>>(wv, wvb);
  k_cvt<<<dim3(256),256,0,stream>>>(wo, wob);

  k_stats1<<<dim3(2048),256,0,stream>>>(x, part);
  k_stats2<<<dim3(8),256,0,stream>>>(part, stats);
  k_norm<<<dim3(64,4,8),256,0,stream>>>(x, lnw, lnb, stats, nx);

  // Q pre-scaled by log2(e)/16 (softmax runs in base-2), K: [seq][dim]; V: [dim][seq]
  k_gemm2<0,0><<<dim3(32,2,8),256,0,stream>>>(nx, (long)(HW_*C_), wqb, 0L, bq, 0.09016844f,
                                              qtb, (long)(HW_*C_), C_, nullptr, nullptr);
  k_gemm2<0,0><<<dim3(32,2,8),256,0,stream>>>(nx, (long)(HW_*C_), wkb, 0L, bk, 1.0f,
                                              ktb, (long)(HW_*C_), C_, nullptr, nullptr);
  k_gemm2<1,0><<<dim3(2,32,8),256,0,stream>>>(wvb, 0L, nx, (long)(HW_*C_), bv, 1.0f,
                                              vvb, (long)(CNT_), HW_, nullptr, nullptr);

  k_attn6<<<dim3(512),256,0,stream>>>(qtb, ktb, vvb, rest, pO1, pml);
  k_merge<<<dim3(4096),256,0,stream>>>(rest, pO1, pml);

  k_gemm2<1,1><<<dim3(2,32,8),256,0,stream>>>(wob, 0L, rest, (long)(HW_*C_), bo, 1.0f,
                                              nullptr, (long)(CNT_), HW_, out, x);
}

// Round 10
// 224.569 us; speedup vs baseline: 2.1671x; 1.2171x over previous
//
#include <hip/hip_runtime.h>
#include <hip/hip_bf16.h>

#define N_ 8
#define C_ 256
#define HW_ 4096
#define CNT_ (C_*HW_)

typedef __attribute__((ext_vector_type(8))) short bf16x8;
typedef __attribute__((ext_vector_type(4))) float f32x4;
typedef __attribute__((ext_vector_type(16))) float f32x16;

__device__ inline float exp2fast(float x){ return __builtin_amdgcn_exp2f(x); }

__device__ inline unsigned short f2bf(float f){
  union{float f; unsigned u;} v; v.f=f;
  unsigned r = v.u + 0x7fff + ((v.u>>16)&1);
  return (unsigned short)(r>>16);
}
__device__ inline float bf2f(unsigned short h){
  union{unsigned u; float f;} v; v.u = ((unsigned)h)<<16; return v.f;
}

__device__ inline f32x4 mfma16(bf16x8 a, bf16x8 b, f32x4 c){
  return __builtin_amdgcn_mfma_f32_16x16x32_bf16(a,b,c,0,0,0);
}
__device__ inline f32x16 mfma32(bf16x8 a, bf16x8 b, f32x16 c){
  return __builtin_amdgcn_mfma_f32_32x32x16_bf16(a,b,c,0,0,0);
}
__device__ inline f32x16 mfma32f8(long a, long b, f32x16 c){
  return __builtin_amdgcn_mfma_f32_32x32x16_fp8_fp8(a,b,c,0,0,0);
}

#define GLL16(gp, lp) __builtin_amdgcn_global_load_lds( \
    (__attribute__((address_space(1))) void*)(gp), \
    (__attribute__((address_space(3))) void*)(lp), 16, 0, 0)

// ---------------- weight convert (fp32 -> bf16) ----------------
__global__ void k_cvt(const float* __restrict__ src, unsigned short* __restrict__ dst){
  int i = blockIdx.x*256 + threadIdx.x;
  dst[i] = f2bf(src[i]);
}

// ---------------- layernorm stats, stage 1 ----------------
__global__ void k_stats1(const float* __restrict__ x, float2* __restrict__ part){
  int n = blockIdx.x >> 8;
  int chunk = blockIdx.x & 255;
  const float4* p = (const float4*)(x + (size_t)n*CNT_ + (size_t)chunk*4096);
  int t = threadIdx.x;
  float s=0.f, s2=0.f;
  #pragma unroll
  for(int i=0;i<4;i++){
    float4 v = p[t + 256*i];
    s  += v.x+v.y+v.z+v.w;
    s2 += v.x*v.x+v.y*v.y+v.z*v.z+v.w*v.w;
  }
  #pragma unroll
  for(int o=32;o;o>>=1){ s += __shfl_down(s,o); s2 += __shfl_down(s2,o); }
  __shared__ float sh[4], sh2[4];
  int lane = t&63, wid = t>>6;
  if(lane==0){ sh[wid]=s; sh2[wid]=s2; }
  __syncthreads();
  if(t==0){
    float2 r; r.x = sh[0]+sh[1]+sh[2]+sh[3]; r.y = sh2[0]+sh2[1]+sh2[2]+sh2[3];
    part[blockIdx.x] = r;
  }
}

// ---------------- layernorm stats, stage 2 ----------------
__global__ void k_stats2(const float2* __restrict__ part, float2* __restrict__ stats){
  int n = blockIdx.x, t = threadIdx.x;
  float2 v = part[n*256 + t];
  float s = v.x, s2 = v.y;
  #pragma unroll
  for(int o=32;o;o>>=1){ s += __shfl_down(s,o); s2 += __shfl_down(s2,o); }
  __shared__ float sh[4], sh2[4];
  int lane = t&63, wid = t>>6;
  if(lane==0){ sh[wid]=s; sh2[wid]=s2; }
  __syncthreads();
  if(t==0){
    s = sh[0]+sh[1]+sh[2]+sh[3];
    s2 = sh2[0]+sh2[1]+sh2[2]+sh2[3];
    float mean = s * (1.f/(float)CNT_);
    float var  = s2 * (1.f/(float)CNT_) - mean*mean;
    float2 r; r.x = mean; r.y = rsqrtf(var + 1e-5f);
    stats[n] = r;
  }
}

// ---------------- normalize + transpose to NHWC bf16 ----------------
__global__ void k_norm(const float* __restrict__ x, const float* __restrict__ lnw,
                       const float* __restrict__ lnb, const float2* __restrict__ stats,
                       unsigned short* __restrict__ nx){
  __shared__ float tile[64][65];
  int n = blockIdx.z, c0 = blockIdx.y*64, p0 = blockIdx.x*64;
  float2 st = stats[n];
  float mu = st.x, rs = st.y;
  int t = threadIdx.x, col = t&63, rw = t>>6;
  #pragma unroll
  for(int pass=0; pass<16; pass++){
    int row = pass*4 + rw;
    size_t gi = (size_t)(c0+row)*HW_ + (p0+col);
    float v = x[(size_t)n*CNT_ + gi];
    tile[row][col] = (v - mu)*rs*lnw[gi] + lnb[gi];
  }
  __syncthreads();
  #pragma unroll
  for(int pass=0; pass<16; pass++){
    int prow = pass*4 + rw;
    nx[((size_t)n*HW_ + p0+prow)*C_ + c0 + col] = f2bf(tile[col][prow]);
  }
}

// ---------------- 128x128-tile B^T GEMM, LDS-staged (dbuf, issue-early) ----------------
// OUT_MODE: 0 = bf16, 1 = fp8-e4m3, 2 = fp32 + residual
__device__ inline void g2_stage(const char* A, const char* B, char* buf,
                                int w, int r8, int s8, int i0, int c0, int kb0){
  int sl = (s8 ^ (r8&7)) << 4;
  #pragma unroll
  for(int q=0;q<4;q++){
    int row = w*32 + q*8 + r8;
    GLL16(A + (size_t)(i0+row)*512 + kb0 + sl, buf + w*4096 + q*1024);
    GLL16(B + (size_t)(c0+row)*512 + kb0 + sl, buf + 16384 + w*4096 + q*1024);
  }
}

template<int BIAS_ROW, int OUT_MODE>
__global__ __launch_bounds__(256, 2) void k_gemm2(
    const unsigned short* __restrict__ Ab, long sA,
    const unsigned short* __restrict__ Bb, long sB,
    const float* __restrict__ bias, float scale,
    void* __restrict__ Outb, long sO, int ldo,
    float* __restrict__ foutb, const float* __restrict__ xres){
  __shared__ __align__(16) char lds[65536];
  int n = blockIdx.z;
  const char* A = (const char*)(Ab + (size_t)n*sA);
  const char* B = (const char*)(Bb + (size_t)n*sB);
  int t = threadIdx.x, w = t>>6, l = t&63;
  int wr = w>>1, wc = w&1, ri = l&15, kq = l>>4;
  int r8 = l>>3, s8 = l&7;
  int i0 = blockIdx.x*128, c0 = blockIdx.y*128;

  f32x4 acc[4][4];
  #pragma unroll
  for(int m=0;m<4;m++)
    #pragma unroll
    for(int nn=0;nn<4;nn++)
      #pragma unroll
      for(int r=0;r<4;r++) acc[m][nn][r] = 0.f;

  g2_stage(A, B, lds, w, r8, s8, i0, c0, 0);
  __syncthreads();

  for(int kt=0; kt<4; ++kt){
    char* buf = lds + (kt&1)*32768;
    if (kt < 3) g2_stage(A, B, lds + ((kt&1)^1)*32768, w, r8, s8, i0, c0, (kt+1)*128);
    __builtin_amdgcn_s_setprio(1);
    #pragma unroll
    for(int kc=0;kc<2;kc++){
      bf16x8 af[4], bfv[4];
      #pragma unroll
      for(int m=0;m<4;m++){
        int row = wr*64 + m*16 + ri;
        af[m] = *(const bf16x8*)(buf + row*128 + ((((kc<<2)|kq) ^ (row&7))<<4));
      }
      #pragma unroll
      for(int nn=0;nn<4;nn++){
        int row = wc*64 + nn*16 + ri;
        bfv[nn] = *(const bf16x8*)(buf + 16384 + row*128 + ((((kc<<2)|kq) ^ (row&7))<<4));
      }
      #pragma unroll
      for(int m=0;m<4;m++)
        #pragma unroll
        for(int nn=0;nn<4;nn++)
          acc[m][nn] = mfma16(af[m], bfv[nn], acc[m][nn]);
    }
    __builtin_amdgcn_s_setprio(0);
    __syncthreads();
  }

  if (OUT_MODE == 2){
    float* fout = foutb + (size_t)n*sO;
    const float* xr = xres + (size_t)n*sO;
    #pragma unroll
    for(int m=0;m<4;m++){
      #pragma unroll
      for(int nn=0;nn<4;nn++){
        #pragma unroll
        for(int r=0;r<4;r++){
          int row = i0 + wr*64 + m*16 + kq*4 + r;
          int col = c0 + wc*64 + nn*16 + ri;
          size_t idx = (size_t)row*ldo + col;
          fout[idx] = acc[m][nn][r] + bias[row] + xr[idx];
        }
      }
    }
  } else if (OUT_MODE == 1){
    unsigned char* O8 = (unsigned char*)Outb + (size_t)n*sO;
    #pragma unroll
    for(int m=0;m<4;m++){
      #pragma unroll
      for(int nn=0;nn<4;nn++){
        #pragma unroll
        for(int r=0;r<4;r++){
          int row = i0 + wr*64 + m*16 + kq*4 + r;
          int col = c0 + wc*64 + nn*16 + ri;
          float d = (acc[m][nn][r] + bias[BIAS_ROW ? row : col])*scale;
          unsigned u;
          asm("v_cvt_pk_fp8_f32 %0, %1, %2" : "=v"(u) : "v"(d), "v"(0.f));
          O8[(size_t)row*ldo + col] = (unsigned char)(u & 0xff);
        }
      }
    }
  } else {
    unsigned short* O = (unsigned short*)Outb + (size_t)n*sO;
    #pragma unroll
    for(int m=0;m<4;m++){
      #pragma unroll
      for(int nn=0;nn<4;nn++){
        #pragma unroll
        for(int r=0;r<4;r++){
          int row = i0 + wr*64 + m*16 + kq*4 + r;
          int col = c0 + wc*64 + nn*16 + ri;
          float d = (acc[m][nn][r] + bias[BIAS_ROW ? row : col])*scale;
          O[(size_t)row*ldo + col] = f2bf(d);
        }
      }
    }
  }
}

// ---------------- flash attention: fp8 QK, bf16 PV, dbuf, issue-early ----------------
// 512 blocks x 256 threads. Block = (batch, q-tile of 128, j-half of 2048).
// Per buf: K fp8 [32][256B] 16B-slot XOR-swizzled (8 KB) + V bf16 [256][80B] (20 KB) = 28 KB.
// Dual-chain QK (Sa: d 0-127, Sb: d 128-255) via mfma_f32_32x32x16_fp8_fp8.
__device__ inline void stage_KV8(const char* kb, const char* vb, char* ldsbuf,
                                 int w, int l, int j0){
  // K: 512 slots of 16B; slot idx = row*16 + s; pre-swizzled source s^(row&15)
  #pragma unroll
  for(int k=0;k<2;k++){
    int idx0 = k*256 + w*64;         // wave-uniform dst slot base
    int idx = idx0 + l;
    int row = idx>>4, s = idx&15;
    GLL16(kb + (size_t)(j0+row)*256 + ((s ^ (row&15))<<4), ldsbuf + idx0*16);
  }
  // V: bf16 [256 rows][80B: 64 data + 16 pad]
  #pragma unroll
  for(int k=0;k<5;k++){
    int g = w*5+k;
    int c = g*64 + l;
    int d = c/5; int sg = c - d*5; sg = (sg==4)?0:sg;
    GLL16(vb + ((size_t)d<<13) + ((size_t)j0<<1) + (sg<<4), ldsbuf + 8192 + (g<<10));
  }
}

__global__ __launch_bounds__(256, 2) void k_attn7(const unsigned char* __restrict__ qt,
                                                  const unsigned char* __restrict__ kt,
                                                  const unsigned short* __restrict__ vv,
                                                  unsigned short* __restrict__ pO0,
                                                  unsigned short* __restrict__ pO1,
                                                  float2* __restrict__ pml){
  __shared__ __align__(16) char lds[57344];     // 2 x (8 KB K + 20 KB V)
  int t = threadIdx.x, w = t>>6, l = t&63, hi = l>>5, lo5 = l&31;
  int nb = blockIdx.x & 7, rem = blockIdx.x >> 3;
  int qb = rem >> 1, jh = rem & 1;
  int q0 = qb*128 + w*32;
  const char* kb = (const char*)(kt + (size_t)nb*HW_*C_);
  const char* vb = (const char*)(vv + (size_t)nb*C_*HW_);
  const char* qp = (const char*)(qt + (size_t)nb*HW_*C_);
  int jbase = jh*2048;

  // Q fragments, fp8: 16 x 8B = 32 VGPR
  long qf8[16];
  #pragma unroll
  for(int ds=0; ds<16; ds++)
    qf8[ds] = *(const long*)(qp + (size_t)(q0+lo5)*256 + ds*16 + hi*8);

  f32x16 o[8];
  #pragma unroll
  for(int dt=0;dt<8;dt++){
    #pragma unroll
    for(int r=0;r<16;r++) o[dt][r]=0.f;
  }
  float m = -1e30f, lsum = 0.f;

  stage_KV8(kb, vb, lds, w, l, jbase);
  __syncthreads();

  for(int it=0; it<64; ++it){
    int cur = it & 1;
    char* bufc = lds + cur*28672;
    if (it < 63) stage_KV8(kb, vb, lds + (cur^1)*28672, w, l, jbase + (it+1)*32);

    // QK^T fp8: S[j][q], lane q=lo5; dual independent chains over d-halves
    f32x16 Sa, Sb;
    #pragma unroll
    for(int r=0;r<16;r++){ Sa[r]=0.f; Sb[r]=0.f; }
    __builtin_amdgcn_s_setprio(1);
    #pragma unroll
    for(int ds=0; ds<8; ds++){
      long ka  = *(const long*)(bufc + lo5*256 + ((ds     ^ (lo5&15))<<4) + hi*8);
      long kb8 = *(const long*)(bufc + lo5*256 + (((ds+8) ^ (lo5&15))<<4) + hi*8);
      Sa = mfma32f8(ka,  qf8[ds],   Sa);
      Sb = mfma32f8(kb8, qf8[ds+8], Sb);
    }
    __builtin_amdgcn_s_setprio(0);
    f32x16 S;
    #pragma unroll
    for(int r=0;r<16;r++) S[r] = Sa[r] + Sb[r];

    // online softmax (base-2; Q,K pre-scaled by sqrt(log2e/16) each)
    float p0 = fmaxf(S[0],S[8]),  p1 = fmaxf(S[1],S[9]);
    float p2 = fmaxf(S[2],S[10]), p3 = fmaxf(S[3],S[11]);
    float p4 = fmaxf(S[4],S[12]), p5 = fmaxf(S[5],S[13]);
    float p6 = fmaxf(S[6],S[14]), p7 = fmaxf(S[7],S[15]);
    p0 = fmaxf(p0,p4); p1 = fmaxf(p1,p5); p2 = fmaxf(p2,p6); p3 = fmaxf(p3,p7);
    float mx = fmaxf(fmaxf(p0,p1), fmaxf(p2,p3));
    { float mA = mx, mB = mx;
      asm("v_permlane32_swap_b32 %0, %1" : "+v"(mA), "+v"(mB));
      mx = fmaxf(mA, mB); }
    if (!__all(mx <= m + 11.5f)){
      float mn = fmaxf(m, mx);
      float al = exp2fast(m - mn);
      lsum *= al;
      #pragma unroll
      for(int dt=0;dt<8;dt++) o[dt] = o[dt] * al;
      m = mn;
    }
    unsigned pk[8];
    float rs = 0.f;
    #pragma unroll
    for(int tt=0;tt<8;tt++){
      float pa = exp2fast(S[2*tt]-m), pb = exp2fast(S[2*tt+1]-m);
      rs += pa + pb;
      unsigned pr;
      asm("v_cvt_pk_bf16_f32 %0, %1, %2" : "=v"(pr) : "v"(pa), "v"(pb));
      pk[tt] = pr;
    }
    { float rA = rs, rB = rs;
      asm("v_permlane32_swap_b32 %0, %1" : "+v"(rA), "+v"(rB));
      lsum += rA + rB; }

    // PV (bf16): O^T[d][q] += V[d][j] * P[q][j]; F-fragments via permlane32_swap
    __builtin_amdgcn_s_setprio(1);
    {
      unsigned a0 = pk[0], b0 = pk[2], a1 = pk[1], b1 = pk[3];
      asm("v_permlane32_swap_b32 %0, %1" : "+v"(a0), "+v"(b0));
      asm("v_permlane32_swap_b32 %0, %1" : "+v"(a1), "+v"(b1));
      union { unsigned u[4]; bf16x8 v; } F0;
      F0.u[0] = a0; F0.u[1] = a1; F0.u[2] = b0; F0.u[3] = b1;
      #pragma unroll
      for(int dt=0;dt<8;dt++){
        bf16x8 v0 = *(const bf16x8*)(bufc + 8192 + (dt*32+lo5)*80 + hi*16);
        o[dt] = mfma32(v0, F0.v, o[dt]);
      }
    }
    {
      unsigned a0 = pk[4], b0 = pk[6], a1 = pk[5], b1 = pk[7];
      asm("v_permlane32_swap_b32 %0, %1" : "+v"(a0), "+v"(b0));
      asm("v_permlane32_swap_b32 %0, %1" : "+v"(a1), "+v"(b1));
      union { unsigned u[4]; bf16x8 v; } F1;
      F1.u[0] = a0; F1.u[1] = a1; F1.u[2] = b0; F1.u[3] = b1;
      #pragma unroll
      for(int dt=0;dt<8;dt++){
        bf16x8 v1 = *(const bf16x8*)(bufc + 8192 + (dt*32+lo5)*80 + 32 + hi*16);
        o[dt] = mfma32(v1, F1.v, o[dt]);
      }
    }
    __builtin_amdgcn_s_setprio(0);
    __syncthreads();
  }

  unsigned short* pb = (jh ? pO1 : pO0) + ((size_t)nb*HW_ + q0 + lo5)*C_;
  #pragma unroll
  for(int dt=0;dt<8;dt++){
    #pragma unroll
    for(int g=0;g<4;g++){
      int d0 = dt*32 + g*8 + hi*4;
      unsigned short h0 = f2bf(o[dt][4*g]);
      unsigned short h1 = f2bf(o[dt][4*g+1]);
      unsigned short h2 = f2bf(o[dt][4*g+2]);
      unsigned short h3 = f2bf(o[dt][4*g+3]);
      uint2 uo; uo.x = (unsigned)h0 | ((unsigned)h1<<16);
      uo.y = (unsigned)h2 | ((unsigned)h3<<16);
      *(uint2*)(pb + d0) = uo;
    }
  }
  if (l < 32){
    float2 ml; ml.x = m; ml.y = lsum;
    pml[(size_t)jh*32768 + (size_t)nb*HW_ + q0 + lo5] = ml;
  }
}

// ---------------- merge the two j-half partials (in place into pO0 = rest) ----------------
__global__ void k_merge(unsigned short* __restrict__ pO0,
                        const unsigned short* __restrict__ pO1,
                        const float2* __restrict__ pml){
  int t = threadIdx.x;
  int row = blockIdx.x*8 + (t>>5);
  int dn = t & 31;
  float2 ml0 = pml[row], ml1 = pml[32768 + row];
  float mN = fmaxf(ml0.x, ml1.x);
  float a0 = exp2fast(ml0.x - mN), a1 = exp2fast(ml1.x - mN);
  float inv = 1.f/(a0*ml0.y + a1*ml1.y);
  float s0 = a0*inv, s1 = a1*inv;
  size_t off = (size_t)row*256 + dn*8;
  uint4 u0 = *(const uint4*)(pO0 + off);
  uint4 u1 = *(const uint4*)(pO1 + off);
  unsigned r[4];
  unsigned w0[4] = {u0.x, u0.y, u0.z, u0.w};
  unsigned w1[4] = {u1.x, u1.y, u1.z, u1.w};
  #pragma unroll
  for(int q=0;q<4;q++){
    float lo = s0*bf2f((unsigned short)(w0[q]&0xffff)) + s1*bf2f((unsigned short)(w1[q]&0xffff));
    float hi = s0*bf2f((unsigned short)(w0[q]>>16))    + s1*bf2f((unsigned short)(w1[q]>>16));
    r[q] = (unsigned)f2bf(lo) | ((unsigned)f2bf(hi)<<16);
  }
  uint4 ru; ru.x=r[0]; ru.y=r[1]; ru.z=r[2]; ru.w=r[3];
  *(uint4*)(pO0 + off) = ru;
}

extern "C" void kernel_launch(void* const* d_in, const int* in_sizes, int n_in,
                              void* d_out, int out_size, void* d_ws, size_t ws_size,
                              hipStream_t stream) {
  const float* x   = (const float*)d_in[0];
  const float* lnw = (const float*)d_in[1];
  const float* lnb = (const float*)d_in[2];
  const float* wq  = (const float*)d_in[3];
  const float* bq  = (const float*)d_in[4];
  const float* wk  = (const float*)d_in[5];
  const float* bk  = (const float*)d_in[6];
  const float* wv  = (const float*)d_in[7];
  const float* bv  = (const float*)d_in[8];
  const float* wo  = (const float*)d_in[9];
  const float* bo  = (const float*)d_in[10];
  float* out = (float*)d_out;

  uintptr_t base = (uintptr_t)d_ws;
  float2* part  = (float2*)base;
  float2* stats = (float2*)(base + 16384);
  unsigned short* wqb = (unsigned short*)(base + 16448);
  unsigned short* wkb = wqb + 65536;
  unsigned short* wvb = wqb + 2*65536;
  unsigned short* wob = wqb + 3*65536;
  unsigned short* nx  = wqb + 4*65536;
  const size_t TEN = (size_t)N_*HW_*C_;
  unsigned short* qtb = nx + TEN;       // used as fp8 (8 MB of the 16 MB slot)
  unsigned short* ktb = qtb + TEN;      // used as fp8
  unsigned short* vvb = ktb + TEN;      // bf16 V [dim][seq]
  unsigned short* pO1 = vvb + TEN;
  float2* pml = (float2*)(pO1 + TEN);
  unsigned short* rest = nx;            // = pO0, merged in place

  k_cvt<<<dim3(256),256,0,stream>>>(wq, wqb);
  k_cvt<<<dim3(256),256,0,stream>>>(wk, wkb);
  k_cvt<<<dim3(256),256,0,stream>>>(wv, wvb);
  k_cvt<<<dim3(256),256,0,stream>>>(wo, wob);

  k_stats1<<<dim3(2048),256,0,stream>>>(x, part);
  k_stats2<<<dim3(8),256,0,stream>>>(part, stats);
  k_norm<<<dim3(64,4,8),256,0,stream>>>(x, lnw, lnb, stats, nx);

  // Q,K in fp8-e4m3, each scaled by sqrt(log2(e)/16) = 0.3002807 -> S in base-2 units.
  // V: bf16 [dim][seq].
  k_gemm2<0,1><<<dim3(32,2,8),256,0,stream>>>(nx, (long)(HW_*C_), wqb, 0L, bq, 0.3002807f,
                                              qtb, (long)(HW_*C_), C_, nullptr, nullptr);
  k_gemm2<0,1><<<dim3(32,2,8),256,0,stream>>>(nx, (long)(HW_*C_), wkb, 0L, bk, 0.3002807f,
                                              ktb, (long)(HW_*C_), C_, nullptr, nullptr);
  k_gemm2<1,0><<<dim3(2,32,8),256,0,stream>>>(wvb, 0L, nx, (long)(HW_*C_), bv, 1.0f,
                                              vvb, (long)(CNT_), HW_, nullptr, nullptr);

  k_attn7<<<dim3(512),256,0,stream>>>((const unsigned char*)qtb, (const unsigned char*)ktb,
                                      vvb, rest, pO1, pml);
  k_merge<<<dim3(4096),256,0,stream>>>(rest, pO1, pml);

  k_gemm2<1,2><<<dim3(2,32,8),256,0,stream>>>(wob, 0L, rest, (long)(HW_*C_), bo, 1.0f,
                                              nullptr, (long)(CNT_), HW_, out, x);
}